// Round 9
// baseline (50832.703 us; speedup 1.0000x reference)
//
#include <hip/hip_runtime.h>
#include <cstddef>
#include <cstdint>

// ---------------------------------------------------------------------------
// PredRNN V1 (L=4, HID=64, 32x32, B=4, T=20 -> 19 steps).
// Round 9: megakernel, SAME phases as round 8 (verified correct, absmax
// 4.9e-4). Only change: the grid barrier. Round 8's single-line counter +
// shared spin line cost ~215us/barrier (256 serialized RMWs starved by 255
// pollers). New barrier: hierarchical arrival (16 L1 lines -> 1 L2) +
// per-block private release flags stored by 256 threads of the releasing
// block. Expected ~2-4us/barrier.
// ---------------------------------------------------------------------------

#define NLAYER 4
#define NSTEP 19
#define GRID 256

typedef _Float16 f16;
typedef _Float16 f16x8 __attribute__((ext_vector_type(8)));
typedef float f32x4 __attribute__((ext_vector_type(4)));

// workspace offsets (in floats)
constexpr size_t OFF_HS    = 0;              // [4][4][64][1024]
constexpr size_t OFF_CS    = 1048576;
constexpr size_t OFF_M     = 2097152;
constexpr size_t OFF_STATS = 2359296;        // 32 doubles
constexpr size_t OFF_XRAW  = 2359360;        // [4][448][1024]
constexpr size_t OFF_HRAW  = 4194368;        // [4][256][1024]
constexpr size_t OFF_MRAW  = 5242944;        // [4][192][1024]
constexpr size_t OFF_MEM   = 6029376;        // [4][128][1024]
constexpr size_t OFF_ORAW  = 6553664;        // [4][64][1024]
constexpr size_t OFF_OXH   = 6815808;        // [4][64][1024]
constexpr size_t OFF_WF    = 7077952;        // f16 region: 12,390,400 f16
constexpr size_t OFF_BAR   = 13273152;       // barrier state: 273 x 64B lines
constexpr size_t BAR_BYTES = 273 * 64;       // L2 cnt + 16 L1 cnt + 256 flags
constexpr size_t ZERO_N    = OFF_XRAW;       // zero hs,cs,m,stats in prologue

// f16-element offsets inside WF
constexpr size_t WF_X0 = 0;
constexpr size_t WF_XR = 716800;             // + lr*1433600
constexpr size_t WF_H  = 5017600;            // + l*819200
constexpr size_t WF_M  = 8294400;            // + l*614400
constexpr size_t WF_O  = 10752000;           // + l*409600

struct P {
    const float* x_patched; const float* mask;
    const float* Wx0; const float* Wxr; const float* Wh;
    const float* Wm; const float* Wo; const float* Wl; const float* Wout;
    float* out;
    float* hs; float* cs; float* m_buf;
    double* stats;
    float* xraw; float* hraw; float* mraw;
    float* mem; float* oraw; float* oxh;
    f16* wfx0; f16* wfxr; f16* wfh; f16* wfm; f16* wfo;
    unsigned* bar;
};

__device__ __forceinline__ float sigmoidf_(float x) {
    return 1.0f / (1.0f + __expf(-x));
}

__device__ __forceinline__ float fast_tanh(float x) {
    float ax = fabsf(x);
    float e = __expf(2.0f * ax);
    float r = 1.0f - 2.0f / (e + 1.0f);
    return copysignf(r, x);
}

__device__ __forceinline__ void ln_params(const double* stats, int slot, int b,
                                          float N, float& mu, float& rs) {
    double s1 = stats[slot * 8 + b * 2 + 0];
    double s2 = stats[slot * 8 + b * 2 + 1];
    double mud = s1 / (double)N;
    double var = s2 / (double)N - mud * mud;
    mu = (float)mud;
    float v = (float)var + 1e-5f;
    float r = rsqrtf(v);
    r = r * (1.5f - 0.5f * v * r * r);
    rs = r;
}

// ------ hierarchical grid barrier: 16x16 arrival + private release flags ---
// st layout (u32, 16-word = 64B slots): slot0 = L2 counter; slots 1..16 =
// L1 counters (block groups of 16); slots 17..272 = per-block flags.
// g = monotonically increasing generation (same sequence in every block).
__device__ __forceinline__ void gridbar(unsigned* st, unsigned g) {
    __shared__ unsigned relf;
    const int tid = threadIdx.x;
    if (tid == 0) relf = 0;
    __syncthreads();                         // phase work done + relf init
    if (tid == 0) {
        __threadfence();
        unsigned* l1 = st + (1 + (blockIdx.x >> 4)) * 16;
        unsigned v = __hip_atomic_fetch_add(l1, 1u, __ATOMIC_ACQ_REL,
                                            __HIP_MEMORY_SCOPE_AGENT);
        if (v == 15u) {
            __hip_atomic_store(l1, 0u, __ATOMIC_RELAXED, __HIP_MEMORY_SCOPE_AGENT);
            unsigned w = __hip_atomic_fetch_add(st, 1u, __ATOMIC_ACQ_REL,
                                                __HIP_MEMORY_SCOPE_AGENT);
            if (w == 15u) {
                __hip_atomic_store(st, 0u, __ATOMIC_RELAXED, __HIP_MEMORY_SCOPE_AGENT);
                relf = 1;                    // this block releases everyone
            }
        }
    }
    __syncthreads();                         // publish relf to all threads
    if (relf) {
        // all 256 threads: one release-store to one block's private flag
        __threadfence();
        __hip_atomic_store(st + (17 + tid) * 16, g, __ATOMIC_RELEASE,
                           __HIP_MEMORY_SCOPE_AGENT);
    } else if (tid == 0) {
        unsigned* myfl = st + (17 + blockIdx.x) * 16;
        while (__hip_atomic_load(myfl, __ATOMIC_ACQUIRE,
                                 __HIP_MEMORY_SCOPE_AGENT) < g)
            __builtin_amdgcn_s_sleep(4);
        __threadfence();
    }
    __syncthreads();
}

// ---- weight prep (device): w[co][ci][5][5] -> [tap][split][co][ci_pad] ----
__device__ void prep_dev(const float* __restrict__ src, f16* __restrict__ dst,
                         int CO, int CIs, int CIp, int gid, int gs) {
    int total = CO * CIp * 25;
    for (int idx = gid; idx < total; idx += gs) {
        int ci = idx % CIp;
        int rem = idx / CIp;
        int co = rem % CO;
        int tap = rem / CO;
        float v = (ci < CIs) ? src[((size_t)co * CIs + ci) * 25 + tap] : 0.f;
        f16 hi = (f16)v;
        f16 lo = (f16)(v - (float)hi);
        dst[((size_t)(tap * 2 + 0) * CO + co) * CIp + ci] = hi;
        dst[((size_t)(tap * 2 + 1) * CO + co) * CIp + ci] = lo;
    }
}

// ---------------- phase A: fused x/h/m gate convs (896 units) --------------
__device__ __forceinline__ void phaseA(const P& p, f16* lds, int t, int l, int u) {
    const int tid = threadIdx.x;
    const int b = u / 224;
    int g = u - b * 224;
    int path, cog, pxg, CO, CI, CIpad;
    const f16* wf;
    const float* in;
    float* outp;
    if (g < 112) {
        path = 0; cog = g >> 4; pxg = g & 15; CO = 448;
        if (l == 0) {
            CI = 16; CIpad = 32; wf = p.wfx0;
            in = p.x_patched + (size_t)b * 327680;       // frame 0 (t==0 only)
        } else {
            CI = 64; CIpad = 64; wf = p.wfxr + (size_t)(l - 1) * 1433600;
            in = p.hs + (size_t)(l - 1) * 262144 + (size_t)b * 65536;
        }
        outp = p.xraw;
    } else if (g < 176) {
        int gg = g - 112;
        path = 1; cog = gg >> 4; pxg = gg & 15; CO = 256; CI = 64; CIpad = 64;
        wf = p.wfh + (size_t)l * 819200;
        in = p.hs + (size_t)l * 262144 + (size_t)b * 65536;
        outp = p.hraw;
    } else {
        int gg = g - 176;
        path = 2; cog = gg >> 4; pxg = gg & 15; CO = 192; CI = 64; CIpad = 64;
        wf = p.wfm + (size_t)l * 614400;
        in = p.m_buf + (size_t)b * 65536;
        outp = p.mraw;
    }
    const int y0 = pxg * 2;
    const bool mix = (path == 0) && (l == 0) && (t > 0);

    const int ci_l = tid & 31, sr = tid >> 5;
    const int skg = ci_l >> 3, scb = ci_l & 7;
    const int sy = y0 - 2 + sr;
    const bool rowok = (sr < 6) && ((unsigned)sy < 32u);

    const int w = tid >> 6, lane = tid & 63;
    const int coh = w & 1, wr = w >> 1;
    const int n = lane & 15, kq = lane >> 4;
    const size_t wtap = (size_t)2 * CO * CIpad;
    const size_t laneA0 = (size_t)(cog * 64 + coh * 32 + n) * CIpad + kq * 8;
    const int pbase = (wr + 2) * 37 + 2 + n;

    f32x4 acc[2][2] = {};

    const int nchunks = CIpad >> 5;
    for (int chunk = 0; chunk < nchunks; ++chunk) {
        __syncthreads();
        {
            const int cig = chunk * 32 + ci_l;
            float v[32];
            #pragma unroll
            for (int k = 0; k < 32; ++k) v[k] = 0.f;
            if (rowok && cig < CI) {
                if (mix) {
                    const float* xfr = p.x_patched + ((size_t)b * 20 + t) * 16384
                                       + (size_t)cig * 1024 + sy * 32;
                    const float* xop = p.out
                                       + (((size_t)b * NSTEP + (t - 1)) * 16 + cig) * 1024
                                       + sy * 32;
                    const float* mkr = p.mask + ((size_t)b * 18 + (t - 1)) * 1024 + sy * 32;
                    #pragma unroll
                    for (int k = 0; k < 8; ++k) {
                        float4 a = *(const float4*)(xfr + k * 4);
                        float4 o = *(const float4*)(xop + k * 4);
                        float4 mm = *(const float4*)(mkr + k * 4);
                        v[4 * k + 0] = mm.x * a.x + (1.f - mm.x) * o.x;
                        v[4 * k + 1] = mm.y * a.y + (1.f - mm.y) * o.y;
                        v[4 * k + 2] = mm.z * a.z + (1.f - mm.z) * o.z;
                        v[4 * k + 3] = mm.w * a.w + (1.f - mm.w) * o.w;
                    }
                } else {
                    const float* rp = in + (size_t)cig * 1024 + sy * 32;
                    #pragma unroll
                    for (int k = 0; k < 8; ++k) {
                        float4 q = *(const float4*)(rp + k * 4);
                        v[4 * k + 0] = q.x; v[4 * k + 1] = q.y;
                        v[4 * k + 2] = q.z; v[4 * k + 3] = q.w;
                    }
                }
            }
            if (sr < 6) {
                #define STW(c, val) { int pp = sr * 37 + (c);                        \
                    int s_ = skg ^ ((pp >> 1) & 3);                                  \
                    int off = pp * 32 + (s_ << 3) + scb;                             \
                    f16 hi = (f16)(val); f16 lo = (f16)((val) - (float)hi);          \
                    lds[off] = hi; lds[7104 + off] = lo; }
                STW(0, 0.f); STW(1, 0.f);
                #pragma unroll
                for (int x = 0; x < 32; ++x) STW(x + 2, v[x]);
                STW(34, 0.f); STW(35, 0.f);
                #undef STW
            }
        }
        __syncthreads();
        const f16* wfc = wf + chunk * 32;
        for (int ky = 0; ky < 5; ++ky) {
            const f16* wfk = wfc + (size_t)(ky * 5) * wtap;
            const int pky = pbase + (ky - 2) * 37;
            #pragma unroll
            for (int kx = 0; kx < 5; ++kx) {
                const f16* wA = wfk + (size_t)kx * wtap;
                const f16* wAl = wA + (size_t)CO * CIpad;
                f16x8 a0h = *(const f16x8*)(wA + laneA0);
                f16x8 a1h = *(const f16x8*)(wA + laneA0 + (size_t)16 * CIpad);
                f16x8 a0l = *(const f16x8*)(wAl + laneA0);
                f16x8 a1l = *(const f16x8*)(wAl + laneA0 + (size_t)16 * CIpad);
                #pragma unroll
                for (int pt = 0; pt < 2; ++pt) {
                    int pp = pky + (kx - 2) + pt * 16;
                    int off = pp * 32 + ((kq ^ ((pp >> 1) & 3)) << 3);
                    f16x8 bh = *(const f16x8*)&lds[off];
                    f16x8 bl = *(const f16x8*)&lds[7104 + off];
                    acc[0][pt] = __builtin_amdgcn_mfma_f32_16x16x32_f16(a0h, bh, acc[0][pt], 0, 0, 0);
                    acc[1][pt] = __builtin_amdgcn_mfma_f32_16x16x32_f16(a1h, bh, acc[1][pt], 0, 0, 0);
                    acc[0][pt] = __builtin_amdgcn_mfma_f32_16x16x32_f16(a0l, bh, acc[0][pt], 0, 0, 0);
                    acc[1][pt] = __builtin_amdgcn_mfma_f32_16x16x32_f16(a1l, bh, acc[1][pt], 0, 0, 0);
                    acc[0][pt] = __builtin_amdgcn_mfma_f32_16x16x32_f16(a0h, bl, acc[0][pt], 0, 0, 0);
                    acc[1][pt] = __builtin_amdgcn_mfma_f32_16x16x32_f16(a1h, bl, acc[1][pt], 0, 0, 0);
                }
            }
        }
    }

    float* ob = outp + ((size_t)b * CO + cog * 64 + coh * 32) * 1024 + (y0 + wr) * 32;
    double s1 = 0.0, s2 = 0.0;
    #pragma unroll
    for (int ct = 0; ct < 2; ++ct)
        #pragma unroll
        for (int pt = 0; pt < 2; ++pt)
            #pragma unroll
            for (int j = 0; j < 4; ++j) {
                float vv = acc[ct][pt][j];
                ob[(size_t)(ct * 16 + kq * 4 + j) * 1024 + pt * 16 + n] = vv;
                s1 += vv; s2 += (double)vv * vv;
            }
    __syncthreads();
    double* red = (double*)lds;
    red[tid] = s1; red[256 + tid] = s2;
    __syncthreads();
    for (int s = 128; s > 0; s >>= 1) {
        if (tid < s) { red[tid] += red[tid + s]; red[256 + tid] += red[256 + tid + s]; }
        __syncthreads();
    }
    if (tid == 0) {
        atomicAdd(&p.stats[path * 8 + b * 2 + 0], red[0]);
        atomicAdd(&p.stats[path * 8 + b * 2 + 1], red[256]);
    }
    __syncthreads();
}

// ---------------------------- phase B: gates -------------------------------
#define LD4(dst, ptr) { float4 _v = *reinterpret_cast<const float4*>(ptr); \
                        (dst)[0]=_v.x; (dst)[1]=_v.y; (dst)[2]=_v.z; (dst)[3]=_v.w; }
#define ST4(ptr, src) { *reinterpret_cast<float4*>(ptr) = \
                        make_float4((src)[0], (src)[1], (src)[2], (src)[3]); }

__device__ __forceinline__ void phaseB(const P& p, int l) {
    int e4 = blockIdx.x * 256 + threadIdx.x;
    if (e4 >= 65536) return;
    if (e4 < 8) p.stats[24 + e4] = 0.0;     // zero slot 3 for conv-o
    int b = e4 >> 14;
    int r = (e4 & 16383) << 2;

    float mu_x, rs_x, mu_h, rs_h, mu_m, rs_m;
    ln_params(p.stats, 0, b, 458752.f, mu_x, rs_x);
    ln_params(p.stats, 1, b, 262144.f, mu_h, rs_h);
    ln_params(p.stats, 2, b, 196608.f, mu_m, rs_m);

    const float* xb = p.xraw + (size_t)b * 458752 + r;
    const float* hb = p.hraw + (size_t)b * 262144 + r;
    const float* mb = p.mraw + (size_t)b * 196608 + r;
    float* csb  = p.cs + (size_t)l * 262144 + (size_t)b * 65536 + r;
    float* mbb  = p.m_buf + (size_t)b * 65536 + r;
    float* memc = p.mem + (size_t)b * 131072 + r;
    float* memm = memc + 65536;
    float* oxb  = p.oxh + (size_t)b * 65536 + r;

    float X[7][4], H[4][4], M[3][4], C[4], MM[4];
    #pragma unroll
    for (int k = 0; k < 7; ++k) LD4(X[k], xb + k * 65536);
    #pragma unroll
    for (int k = 0; k < 4; ++k) LD4(H[k], hb + k * 65536);
    #pragma unroll
    for (int k = 0; k < 3; ++k) LD4(M[k], mb + k * 65536);
    LD4(C, csb);
    LD4(MM, mbb);

    float cn[4], mn[4], ox4[4];
    #pragma unroll
    for (int j = 0; j < 4; ++j) {
        float ix  = (X[0][j] - mu_x) * rs_x;
        float fx  = (X[1][j] - mu_x) * rs_x;
        float gx  = (X[2][j] - mu_x) * rs_x;
        float ixp = (X[3][j] - mu_x) * rs_x;
        float fxp = (X[4][j] - mu_x) * rs_x;
        float gxp = (X[5][j] - mu_x) * rs_x;
        float ox  = (X[6][j] - mu_x) * rs_x;
        float ih  = (H[0][j] - mu_h) * rs_h;
        float fh  = (H[1][j] - mu_h) * rs_h;
        float gh  = (H[2][j] - mu_h) * rs_h;
        float oh  = (H[3][j] - mu_h) * rs_h;
        float im  = (M[0][j] - mu_m) * rs_m;
        float fm  = (M[1][j] - mu_m) * rs_m;
        float gm  = (M[2][j] - mu_m) * rs_m;

        float i  = sigmoidf_(ix + ih);
        float f  = sigmoidf_(fx + fh + 1.0f);
        float gg = fast_tanh(gx + gh);
        float c  = f * C[j] + i * gg;
        float ip = sigmoidf_(ixp + im);
        float fp = sigmoidf_(fxp + fm + 1.0f);
        float gp = fast_tanh(gxp + gm);
        float m2 = fp * MM[j] + ip * gp;
        cn[j] = c; mn[j] = m2; ox4[j] = ox + oh;
    }
    ST4(csb, cn); ST4(mbb, mn); ST4(memc, cn); ST4(memm, mn); ST4(oxb, ox4);
}

// ------------- phase C: conv-o (full 128ci per block) + stats --------------
__device__ __forceinline__ void phaseC(const P& p, f16* lds, int l) {
    const int bid = blockIdx.x;
    const int tid = threadIdx.x;
    if (bid >= 128) {
        if (bid == 128 && tid < 24) p.stats[tid] = 0.0;   // zero slots 0-2
        return;
    }
    const int b = bid >> 5;
    const int pxg = (bid >> 1) & 15;
    const int coh = bid & 1;
    const int y0 = pxg * 2;
    const float* in = p.mem + (size_t)b * 131072;
    const f16* wfo = p.wfo + (size_t)l * 409600;

    const int ci_l = tid & 31, sr = tid >> 5;
    const int skg = ci_l >> 3, scb = ci_l & 7;
    const int sy = y0 - 2 + sr;
    const bool rowok = (sr < 6) && ((unsigned)sy < 32u);

    const int w = tid >> 6, lane = tid & 63;
    const int coq = w & 1, wr = w >> 1;
    const int n = lane & 15, kq = lane >> 4;
    const size_t wtap = (size_t)2 * 64 * 128;
    const int pbase = (wr + 2) * 37 + 2 + n;

    f32x4 acc[2] = {};

    for (int chunk = 0; chunk < 4; ++chunk) {
        __syncthreads();
        {
            const int cig = chunk * 32 + ci_l;
            float v[32];
            #pragma unroll
            for (int k = 0; k < 32; ++k) v[k] = 0.f;
            if (rowok) {
                const float* rp = in + (size_t)cig * 1024 + sy * 32;
                #pragma unroll
                for (int k = 0; k < 8; ++k) {
                    float4 q = *(const float4*)(rp + k * 4);
                    v[4 * k + 0] = q.x; v[4 * k + 1] = q.y;
                    v[4 * k + 2] = q.z; v[4 * k + 3] = q.w;
                }
            }
            if (sr < 6) {
                #define STW(c, val) { int pp = sr * 37 + (c);                        \
                    int s_ = skg ^ ((pp >> 1) & 3);                                  \
                    int off = pp * 32 + (s_ << 3) + scb;                             \
                    f16 hi = (f16)(val); f16 lo = (f16)((val) - (float)hi);          \
                    lds[off] = hi; lds[7104 + off] = lo; }
                STW(0, 0.f); STW(1, 0.f);
                #pragma unroll
                for (int x = 0; x < 32; ++x) STW(x + 2, v[x]);
                STW(34, 0.f); STW(35, 0.f);
                #undef STW
            }
        }
        __syncthreads();
        const size_t laneA = (size_t)(coh * 32 + coq * 16 + n) * 128 + chunk * 32 + kq * 8;
        for (int ky = 0; ky < 5; ++ky) {
            const f16* wfk = wfo + (size_t)(ky * 5) * wtap;
            const int pky = pbase + (ky - 2) * 37;
            #pragma unroll
            for (int kx = 0; kx < 5; ++kx) {
                const f16* wA = wfk + (size_t)kx * wtap;
                f16x8 ah = *(const f16x8*)(wA + laneA);
                f16x8 al = *(const f16x8*)(wA + (size_t)64 * 128 + laneA);
                #pragma unroll
                for (int pt = 0; pt < 2; ++pt) {
                    int pp = pky + (kx - 2) + pt * 16;
                    int off = pp * 32 + ((kq ^ ((pp >> 1) & 3)) << 3);
                    f16x8 bh = *(const f16x8*)&lds[off];
                    f16x8 bl = *(const f16x8*)&lds[7104 + off];
                    acc[pt] = __builtin_amdgcn_mfma_f32_16x16x32_f16(ah, bh, acc[pt], 0, 0, 0);
                    acc[pt] = __builtin_amdgcn_mfma_f32_16x16x32_f16(al, bh, acc[pt], 0, 0, 0);
                    acc[pt] = __builtin_amdgcn_mfma_f32_16x16x32_f16(ah, bl, acc[pt], 0, 0, 0);
                }
            }
        }
    }

    float* ob = p.oraw + ((size_t)b * 64 + coh * 32 + coq * 16) * 1024 + (y0 + wr) * 32;
    double s1 = 0.0, s2 = 0.0;
    #pragma unroll
    for (int pt = 0; pt < 2; ++pt)
        #pragma unroll
        for (int j = 0; j < 4; ++j) {
            float vv = acc[pt][j];
            ob[(size_t)(kq * 4 + j) * 1024 + pt * 16 + n] = vv;
            s1 += vv; s2 += (double)vv * vv;
        }
    __syncthreads();
    double* red = (double*)lds;
    red[tid] = s1; red[256 + tid] = s2;
    __syncthreads();
    for (int s = 128; s > 0; s >>= 1) {
        if (tid < s) { red[tid] += red[tid + s]; red[256 + tid] += red[256 + tid + s]; }
        __syncthreads();
    }
    if (tid == 0) {
        atomicAdd(&p.stats[24 + b * 2 + 0], red[0]);
        atomicAdd(&p.stats[24 + b * 2 + 1], red[256]);
    }
}

// ---------- phase D: o-gate + 1x1 conv_last + h_new (256 units) ------------
__device__ __forceinline__ void phaseD(const P& p, int l) {
    const int bid = blockIdx.x;
    if (bid >= 256) return;
    const int tid = threadIdx.x;
    const int b = bid >> 6;
    const int pxq = (bid >> 2) & 15;
    const int coq = bid & 3;
    const int px = pxq * 64 + (tid & 63);
    const int co0 = coq * 16 + (tid >> 6) * 4;
    const float* memb = p.mem + (size_t)b * 131072 + px;
    const float* Wl_l = p.Wl + (size_t)l * 8192;
    float acc[4] = {0.f, 0.f, 0.f, 0.f};
    for (int ci = 0; ci < 128; ++ci) {
        float v = memb[ci * 1024];
        #pragma unroll
        for (int k = 0; k < 4; ++k)
            acc[k] = fmaf(v, Wl_l[(co0 + k) * 128 + ci], acc[k]);
    }
    float mu, rs;
    ln_params(p.stats, 3, b, 65536.f, mu, rs);
    float* hs_l = p.hs + (size_t)l * 262144;
    #pragma unroll
    for (int k = 0; k < 4; ++k) {
        size_t idx = ((size_t)b * 64 + co0 + k) * 1024 + px;
        float o = sigmoidf_(p.oxh[idx] + (p.oraw[idx] - mu) * rs);
        hs_l[idx] = o * fast_tanh(acc[k]);
    }
}

// ----------------- phase OUT: 1x1 output conv (64 -> 16) -------------------
__device__ __forceinline__ void phaseOUT(const P& p, int t) {
    int gid = blockIdx.x * 256 + threadIdx.x;
    if (gid >= 4096) return;
    int b = gid >> 10, px = gid & 1023;
    const float* hb = p.hs + (size_t)3 * 262144 + (size_t)b * 65536 + px;
    float acc[16];
    #pragma unroll
    for (int k = 0; k < 16; ++k) acc[k] = 0.f;
    for (int ci = 0; ci < 64; ++ci) {
        float v = hb[ci * 1024];
        #pragma unroll
        for (int k = 0; k < 16; ++k) acc[k] = fmaf(v, p.Wout[k * 64 + ci], acc[k]);
    }
    #pragma unroll
    for (int k = 0; k < 16; ++k)
        p.out[(((size_t)b * NSTEP + t) * 16 + k) * 1024 + px] = acc[k];
}

// ------------------------------ megakernel ---------------------------------
__global__ __launch_bounds__(256, 2)
void mega_k(P p) {
    __shared__ alignas(16) f16 lds[14208];

    // ---- prologue: zero state/stats + weight prep ----
    {
        const int gid = blockIdx.x * 256 + threadIdx.x;
        const int gs = GRID * 256;
        float4 z = make_float4(0.f, 0.f, 0.f, 0.f);
        for (size_t i = (size_t)gid * 4; i < ZERO_N; i += (size_t)gs * 4)
            *reinterpret_cast<float4*>(p.hs + i) = z;
        prep_dev(p.Wx0, p.wfx0, 448, 16, 32, gid, gs);
        for (int lr = 0; lr < 3; ++lr)
            prep_dev(p.Wxr + (size_t)lr * 716800, p.wfxr + (size_t)lr * 1433600,
                     448, 64, 64, gid, gs);
        for (int l = 0; l < 4; ++l) {
            prep_dev(p.Wh + (size_t)l * 409600, p.wfh + (size_t)l * 819200,
                     256, 64, 64, gid, gs);
            prep_dev(p.Wm + (size_t)l * 307200, p.wfm + (size_t)l * 614400,
                     192, 64, 64, gid, gs);
            prep_dev(p.Wo + (size_t)l * 204800, p.wfo + (size_t)l * 409600,
                     64, 128, 128, gid, gs);
        }
    }
    unsigned gen = 0;
    gridbar(p.bar, ++gen);

    for (int t = 0; t < NSTEP; ++t) {
        for (int l = 0; l < NLAYER; ++l) {
            for (int u = blockIdx.x; u < 896; u += GRID)
                phaseA(p, lds, t, l, u);
            gridbar(p.bar, ++gen);
            phaseB(p, l);
            gridbar(p.bar, ++gen);
            phaseC(p, lds, l);
            gridbar(p.bar, ++gen);
            phaseD(p, l);
            gridbar(p.bar, ++gen);
        }
        phaseOUT(p, t);
        gridbar(p.bar, ++gen);
    }
}

// ---------------------------------------------------------------------------
extern "C" void kernel_launch(void* const* d_in, const int* in_sizes, int n_in,
                              void* d_out, int out_size, void* d_ws, size_t ws_size,
                              hipStream_t stream) {
    float* ws = (float*)d_ws;
    P pv;
    pv.x_patched = (const float*)d_in[0];
    pv.mask      = (const float*)d_in[1];
    pv.Wx0       = (const float*)d_in[2];
    pv.Wxr       = (const float*)d_in[3];
    pv.Wh        = (const float*)d_in[4];
    pv.Wm        = (const float*)d_in[5];
    pv.Wo        = (const float*)d_in[6];
    pv.Wl        = (const float*)d_in[7];
    pv.Wout      = (const float*)d_in[8];
    pv.out   = (float*)d_out;
    pv.hs    = ws + OFF_HS;
    pv.cs    = ws + OFF_CS;
    pv.m_buf = ws + OFF_M;
    pv.stats = (double*)(ws + OFF_STATS);
    pv.xraw  = ws + OFF_XRAW;
    pv.hraw  = ws + OFF_HRAW;
    pv.mraw  = ws + OFF_MRAW;
    pv.mem   = ws + OFF_MEM;
    pv.oraw  = ws + OFF_ORAW;
    pv.oxh   = ws + OFF_OXH;
    f16* wfb = (f16*)(ws + OFF_WF);
    pv.wfx0 = wfb + WF_X0;
    pv.wfxr = wfb + WF_XR;
    pv.wfh  = wfb + WF_H;
    pv.wfm  = wfb + WF_M;
    pv.wfo  = wfb + WF_O;
    pv.bar  = (unsigned*)(ws + OFF_BAR);

    // barrier state must start at 0 (d_ws is poisoned before every launch)
    hipMemsetAsync((void*)pv.bar, 0, BAR_BYTES, stream);

    mega_k<<<dim3(GRID), dim3(256), 0, stream>>>(pv);

    (void)in_sizes; (void)n_in; (void)out_size; (void)ws_size;
}

// Round 10
// 19113.768 us; speedup vs baseline: 2.6595x; 2.6595x over previous
//
#include <hip/hip_runtime.h>
#include <cstddef>
#include <cstdint>

// ---------------------------------------------------------------------------
// PredRNN V1 (L=4, HID=64, 32x32, B=4, T=20 -> 19 steps).
// Round 10: megakernel, phases identical to rounds 8/9 (verified, absmax
// 4.9e-4). Only change: barrier memory-ordering. R8/R9 used ACQ_REL RMWs and
// acquire-loads in the spin loop -- on gfx950 each emits buffer_wbl2/
// buffer_inv (FULL L2 writeback/invalidate). 255 blocks polling with acquire
// = thousands of L2 invalidates/ms -> 11.8 GB FETCH_SIZE, MfmaUtil 2.7%.
// New barrier: RELAXED atomics everywhere (agent-scope sc1 = coherent at
// fabric, no cache maintenance) + exactly ONE release fence before arrival
// and ONE acquire fence after release per block per barrier.
// ---------------------------------------------------------------------------

#define NLAYER 4
#define NSTEP 19
#define GRID 256

typedef _Float16 f16;
typedef _Float16 f16x8 __attribute__((ext_vector_type(8)));
typedef float f32x4 __attribute__((ext_vector_type(4)));

// workspace offsets (in floats)
constexpr size_t OFF_HS    = 0;              // [4][4][64][1024]
constexpr size_t OFF_CS    = 1048576;
constexpr size_t OFF_M     = 2097152;
constexpr size_t OFF_STATS = 2359296;        // 32 doubles
constexpr size_t OFF_XRAW  = 2359360;        // [4][448][1024]
constexpr size_t OFF_HRAW  = 4194368;        // [4][256][1024]
constexpr size_t OFF_MRAW  = 5242944;        // [4][192][1024]
constexpr size_t OFF_MEM   = 6029376;        // [4][128][1024]
constexpr size_t OFF_ORAW  = 6553664;        // [4][64][1024]
constexpr size_t OFF_OXH   = 6815808;        // [4][64][1024]
constexpr size_t OFF_WF    = 7077952;        // f16 region: 12,390,400 f16
constexpr size_t OFF_BAR   = 13273152;       // barrier state: 273 x 64B lines
constexpr size_t BAR_BYTES = 273 * 64;       // L2 cnt + 16 L1 cnt + 256 flags
constexpr size_t ZERO_N    = OFF_XRAW;       // zero hs,cs,m,stats in prologue

// f16-element offsets inside WF
constexpr size_t WF_X0 = 0;
constexpr size_t WF_XR = 716800;             // + lr*1433600
constexpr size_t WF_H  = 5017600;            // + l*819200
constexpr size_t WF_M  = 8294400;            // + l*614400
constexpr size_t WF_O  = 10752000;           // + l*409600

struct P {
    const float* x_patched; const float* mask;
    const float* Wx0; const float* Wxr; const float* Wh;
    const float* Wm; const float* Wo; const float* Wl; const float* Wout;
    float* out;
    float* hs; float* cs; float* m_buf;
    double* stats;
    float* xraw; float* hraw; float* mraw;
    float* mem; float* oraw; float* oxh;
    f16* wfx0; f16* wfxr; f16* wfh; f16* wfm; f16* wfo;
    unsigned* bar;
};

__device__ __forceinline__ float sigmoidf_(float x) {
    return 1.0f / (1.0f + __expf(-x));
}

__device__ __forceinline__ float fast_tanh(float x) {
    float ax = fabsf(x);
    float e = __expf(2.0f * ax);
    float r = 1.0f - 2.0f / (e + 1.0f);
    return copysignf(r, x);
}

__device__ __forceinline__ void ln_params(const double* stats, int slot, int b,
                                          float N, float& mu, float& rs) {
    double s1 = stats[slot * 8 + b * 2 + 0];
    double s2 = stats[slot * 8 + b * 2 + 1];
    double mud = s1 / (double)N;
    double var = s2 / (double)N - mud * mud;
    mu = (float)mud;
    float v = (float)var + 1e-5f;
    float r = rsqrtf(v);
    r = r * (1.5f - 0.5f * v * r * r);
    rs = r;
}

// ---- minimal-fence hierarchical grid barrier ------------------------------
// st layout (u32, 16-word = 64B slots): slot0 = L2 counter; slots 1..16 =
// L1 counters (block groups of 16); slots 17..272 = per-block flags.
// g = monotonically increasing generation (identical sequence in all blocks).
// Exactly one wbl2 (release fence) and one inv (acquire fence) per block.
__device__ __forceinline__ void gridbar(unsigned* st, unsigned g) {
    __shared__ unsigned relf;
    const int tid = threadIdx.x;
    if (tid == 0) relf = 0;
    __syncthreads();                          // phase work done + relf init
    if (tid == 0) {
        // single writeback: publish this block's phase stores to fabric
        __builtin_amdgcn_fence(__ATOMIC_RELEASE, "agent");
        unsigned* l1 = st + (1 + (blockIdx.x >> 4)) * 16;
        unsigned v = __hip_atomic_fetch_add(l1, 1u, __ATOMIC_RELAXED,
                                            __HIP_MEMORY_SCOPE_AGENT);
        if (v == 15u) {
            __hip_atomic_store(l1, 0u, __ATOMIC_RELAXED, __HIP_MEMORY_SCOPE_AGENT);
            unsigned w = __hip_atomic_fetch_add(st, 1u, __ATOMIC_RELAXED,
                                                __HIP_MEMORY_SCOPE_AGENT);
            if (w == 15u) {
                __hip_atomic_store(st, 0u, __ATOMIC_RELAXED, __HIP_MEMORY_SCOPE_AGENT);
                relf = 1;                     // this block releases everyone
            }
        }
    }
    __syncthreads();                          // publish relf
    if (relf) {
        // 256 threads: one relaxed store each to one block's private flag
        __hip_atomic_store(st + (17 + tid) * 16, g, __ATOMIC_RELAXED,
                           __HIP_MEMORY_SCOPE_AGENT);
    } else if (tid == 0) {
        unsigned* myfl = st + (17 + blockIdx.x) * 16;
        while (__hip_atomic_load(myfl, __ATOMIC_RELAXED,
                                 __HIP_MEMORY_SCOPE_AGENT) < g)
            __builtin_amdgcn_s_sleep(16);
    }
    __syncthreads();
    if (tid == 0)
        // single invalidate: drop stale L1/L2 lines before reading peers' data
        __builtin_amdgcn_fence(__ATOMIC_ACQUIRE, "agent");
    __syncthreads();
}

// ---- weight prep (device): w[co][ci][5][5] -> [tap][split][co][ci_pad] ----
__device__ void prep_dev(const float* __restrict__ src, f16* __restrict__ dst,
                         int CO, int CIs, int CIp, int gid, int gs) {
    int total = CO * CIp * 25;
    for (int idx = gid; idx < total; idx += gs) {
        int ci = idx % CIp;
        int rem = idx / CIp;
        int co = rem % CO;
        int tap = rem / CO;
        float v = (ci < CIs) ? src[((size_t)co * CIs + ci) * 25 + tap] : 0.f;
        f16 hi = (f16)v;
        f16 lo = (f16)(v - (float)hi);
        dst[((size_t)(tap * 2 + 0) * CO + co) * CIp + ci] = hi;
        dst[((size_t)(tap * 2 + 1) * CO + co) * CIp + ci] = lo;
    }
}

// ---------------- phase A: fused x/h/m gate convs (896 units) --------------
__device__ __forceinline__ void phaseA(const P& p, f16* lds, int t, int l, int u) {
    const int tid = threadIdx.x;
    const int b = u / 224;
    int g = u - b * 224;
    int path, cog, pxg, CO, CI, CIpad;
    const f16* wf;
    const float* in;
    float* outp;
    if (g < 112) {
        path = 0; cog = g >> 4; pxg = g & 15; CO = 448;
        if (l == 0) {
            CI = 16; CIpad = 32; wf = p.wfx0;
            in = p.x_patched + (size_t)b * 327680;       // frame 0 (t==0 only)
        } else {
            CI = 64; CIpad = 64; wf = p.wfxr + (size_t)(l - 1) * 1433600;
            in = p.hs + (size_t)(l - 1) * 262144 + (size_t)b * 65536;
        }
        outp = p.xraw;
    } else if (g < 176) {
        int gg = g - 112;
        path = 1; cog = gg >> 4; pxg = gg & 15; CO = 256; CI = 64; CIpad = 64;
        wf = p.wfh + (size_t)l * 819200;
        in = p.hs + (size_t)l * 262144 + (size_t)b * 65536;
        outp = p.hraw;
    } else {
        int gg = g - 176;
        path = 2; cog = gg >> 4; pxg = gg & 15; CO = 192; CI = 64; CIpad = 64;
        wf = p.wfm + (size_t)l * 614400;
        in = p.m_buf + (size_t)b * 65536;
        outp = p.mraw;
    }
    const int y0 = pxg * 2;
    const bool mix = (path == 0) && (l == 0) && (t > 0);

    const int ci_l = tid & 31, sr = tid >> 5;
    const int skg = ci_l >> 3, scb = ci_l & 7;
    const int sy = y0 - 2 + sr;
    const bool rowok = (sr < 6) && ((unsigned)sy < 32u);

    const int w = tid >> 6, lane = tid & 63;
    const int coh = w & 1, wr = w >> 1;
    const int n = lane & 15, kq = lane >> 4;
    const size_t wtap = (size_t)2 * CO * CIpad;
    const size_t laneA0 = (size_t)(cog * 64 + coh * 32 + n) * CIpad + kq * 8;
    const int pbase = (wr + 2) * 37 + 2 + n;

    f32x4 acc[2][2] = {};

    const int nchunks = CIpad >> 5;
    for (int chunk = 0; chunk < nchunks; ++chunk) {
        __syncthreads();
        {
            const int cig = chunk * 32 + ci_l;
            float v[32];
            #pragma unroll
            for (int k = 0; k < 32; ++k) v[k] = 0.f;
            if (rowok && cig < CI) {
                if (mix) {
                    const float* xfr = p.x_patched + ((size_t)b * 20 + t) * 16384
                                       + (size_t)cig * 1024 + sy * 32;
                    const float* xop = p.out
                                       + (((size_t)b * NSTEP + (t - 1)) * 16 + cig) * 1024
                                       + sy * 32;
                    const float* mkr = p.mask + ((size_t)b * 18 + (t - 1)) * 1024 + sy * 32;
                    #pragma unroll
                    for (int k = 0; k < 8; ++k) {
                        float4 a = *(const float4*)(xfr + k * 4);
                        float4 o = *(const float4*)(xop + k * 4);
                        float4 mm = *(const float4*)(mkr + k * 4);
                        v[4 * k + 0] = mm.x * a.x + (1.f - mm.x) * o.x;
                        v[4 * k + 1] = mm.y * a.y + (1.f - mm.y) * o.y;
                        v[4 * k + 2] = mm.z * a.z + (1.f - mm.z) * o.z;
                        v[4 * k + 3] = mm.w * a.w + (1.f - mm.w) * o.w;
                    }
                } else {
                    const float* rp = in + (size_t)cig * 1024 + sy * 32;
                    #pragma unroll
                    for (int k = 0; k < 8; ++k) {
                        float4 q = *(const float4*)(rp + k * 4);
                        v[4 * k + 0] = q.x; v[4 * k + 1] = q.y;
                        v[4 * k + 2] = q.z; v[4 * k + 3] = q.w;
                    }
                }
            }
            if (sr < 6) {
                #define STW(c, val) { int pp = sr * 37 + (c);                        \
                    int s_ = skg ^ ((pp >> 1) & 3);                                  \
                    int off = pp * 32 + (s_ << 3) + scb;                             \
                    f16 hi = (f16)(val); f16 lo = (f16)((val) - (float)hi);          \
                    lds[off] = hi; lds[7104 + off] = lo; }
                STW(0, 0.f); STW(1, 0.f);
                #pragma unroll
                for (int x = 0; x < 32; ++x) STW(x + 2, v[x]);
                STW(34, 0.f); STW(35, 0.f);
                #undef STW
            }
        }
        __syncthreads();
        const f16* wfc = wf + chunk * 32;
        for (int ky = 0; ky < 5; ++ky) {
            const f16* wfk = wfc + (size_t)(ky * 5) * wtap;
            const int pky = pbase + (ky - 2) * 37;
            #pragma unroll
            for (int kx = 0; kx < 5; ++kx) {
                const f16* wA = wfk + (size_t)kx * wtap;
                const f16* wAl = wA + (size_t)CO * CIpad;
                f16x8 a0h = *(const f16x8*)(wA + laneA0);
                f16x8 a1h = *(const f16x8*)(wA + laneA0 + (size_t)16 * CIpad);
                f16x8 a0l = *(const f16x8*)(wAl + laneA0);
                f16x8 a1l = *(const f16x8*)(wAl + laneA0 + (size_t)16 * CIpad);
                #pragma unroll
                for (int pt = 0; pt < 2; ++pt) {
                    int pp = pky + (kx - 2) + pt * 16;
                    int off = pp * 32 + ((kq ^ ((pp >> 1) & 3)) << 3);
                    f16x8 bh = *(const f16x8*)&lds[off];
                    f16x8 bl = *(const f16x8*)&lds[7104 + off];
                    acc[0][pt] = __builtin_amdgcn_mfma_f32_16x16x32_f16(a0h, bh, acc[0][pt], 0, 0, 0);
                    acc[1][pt] = __builtin_amdgcn_mfma_f32_16x16x32_f16(a1h, bh, acc[1][pt], 0, 0, 0);
                    acc[0][pt] = __builtin_amdgcn_mfma_f32_16x16x32_f16(a0l, bh, acc[0][pt], 0, 0, 0);
                    acc[1][pt] = __builtin_amdgcn_mfma_f32_16x16x32_f16(a1l, bh, acc[1][pt], 0, 0, 0);
                    acc[0][pt] = __builtin_amdgcn_mfma_f32_16x16x32_f16(a0h, bl, acc[0][pt], 0, 0, 0);
                    acc[1][pt] = __builtin_amdgcn_mfma_f32_16x16x32_f16(a1h, bl, acc[1][pt], 0, 0, 0);
                }
            }
        }
    }

    float* ob = outp + ((size_t)b * CO + cog * 64 + coh * 32) * 1024 + (y0 + wr) * 32;
    double s1 = 0.0, s2 = 0.0;
    #pragma unroll
    for (int ct = 0; ct < 2; ++ct)
        #pragma unroll
        for (int pt = 0; pt < 2; ++pt)
            #pragma unroll
            for (int j = 0; j < 4; ++j) {
                float vv = acc[ct][pt][j];
                ob[(size_t)(ct * 16 + kq * 4 + j) * 1024 + pt * 16 + n] = vv;
                s1 += vv; s2 += (double)vv * vv;
            }
    __syncthreads();
    double* red = (double*)lds;
    red[tid] = s1; red[256 + tid] = s2;
    __syncthreads();
    for (int s = 128; s > 0; s >>= 1) {
        if (tid < s) { red[tid] += red[tid + s]; red[256 + tid] += red[256 + tid + s]; }
        __syncthreads();
    }
    if (tid == 0) {
        atomicAdd(&p.stats[path * 8 + b * 2 + 0], red[0]);
        atomicAdd(&p.stats[path * 8 + b * 2 + 1], red[256]);
    }
    __syncthreads();
}

// ---------------------------- phase B: gates -------------------------------
#define LD4(dst, ptr) { float4 _v = *reinterpret_cast<const float4*>(ptr); \
                        (dst)[0]=_v.x; (dst)[1]=_v.y; (dst)[2]=_v.z; (dst)[3]=_v.w; }
#define ST4(ptr, src) { *reinterpret_cast<float4*>(ptr) = \
                        make_float4((src)[0], (src)[1], (src)[2], (src)[3]); }

__device__ __forceinline__ void phaseB(const P& p, int l) {
    int e4 = blockIdx.x * 256 + threadIdx.x;
    if (e4 >= 65536) return;
    if (e4 < 8) p.stats[24 + e4] = 0.0;     // zero slot 3 for conv-o
    int b = e4 >> 14;
    int r = (e4 & 16383) << 2;

    float mu_x, rs_x, mu_h, rs_h, mu_m, rs_m;
    ln_params(p.stats, 0, b, 458752.f, mu_x, rs_x);
    ln_params(p.stats, 1, b, 262144.f, mu_h, rs_h);
    ln_params(p.stats, 2, b, 196608.f, mu_m, rs_m);

    const float* xb = p.xraw + (size_t)b * 458752 + r;
    const float* hb = p.hraw + (size_t)b * 262144 + r;
    const float* mb = p.mraw + (size_t)b * 196608 + r;
    float* csb  = p.cs + (size_t)l * 262144 + (size_t)b * 65536 + r;
    float* mbb  = p.m_buf + (size_t)b * 65536 + r;
    float* memc = p.mem + (size_t)b * 131072 + r;
    float* memm = memc + 65536;
    float* oxb  = p.oxh + (size_t)b * 65536 + r;

    float X[7][4], H[4][4], M[3][4], C[4], MM[4];
    #pragma unroll
    for (int k = 0; k < 7; ++k) LD4(X[k], xb + k * 65536);
    #pragma unroll
    for (int k = 0; k < 4; ++k) LD4(H[k], hb + k * 65536);
    #pragma unroll
    for (int k = 0; k < 3; ++k) LD4(M[k], mb + k * 65536);
    LD4(C, csb);
    LD4(MM, mbb);

    float cn[4], mn[4], ox4[4];
    #pragma unroll
    for (int j = 0; j < 4; ++j) {
        float ix  = (X[0][j] - mu_x) * rs_x;
        float fx  = (X[1][j] - mu_x) * rs_x;
        float gx  = (X[2][j] - mu_x) * rs_x;
        float ixp = (X[3][j] - mu_x) * rs_x;
        float fxp = (X[4][j] - mu_x) * rs_x;
        float gxp = (X[5][j] - mu_x) * rs_x;
        float ox  = (X[6][j] - mu_x) * rs_x;
        float ih  = (H[0][j] - mu_h) * rs_h;
        float fh  = (H[1][j] - mu_h) * rs_h;
        float gh  = (H[2][j] - mu_h) * rs_h;
        float oh  = (H[3][j] - mu_h) * rs_h;
        float im  = (M[0][j] - mu_m) * rs_m;
        float fm  = (M[1][j] - mu_m) * rs_m;
        float gm  = (M[2][j] - mu_m) * rs_m;

        float i  = sigmoidf_(ix + ih);
        float f  = sigmoidf_(fx + fh + 1.0f);
        float gg = fast_tanh(gx + gh);
        float c  = f * C[j] + i * gg;
        float ip = sigmoidf_(ixp + im);
        float fp = sigmoidf_(fxp + fm + 1.0f);
        float gp = fast_tanh(gxp + gm);
        float m2 = fp * MM[j] + ip * gp;
        cn[j] = c; mn[j] = m2; ox4[j] = ox + oh;
    }
    ST4(csb, cn); ST4(mbb, mn); ST4(memc, cn); ST4(memm, mn); ST4(oxb, ox4);
}

// ------------- phase C: conv-o (full 128ci per block) + stats --------------
__device__ __forceinline__ void phaseC(const P& p, f16* lds, int l) {
    const int bid = blockIdx.x;
    const int tid = threadIdx.x;
    if (bid >= 128) {
        if (bid == 128 && tid < 24) p.stats[tid] = 0.0;   // zero slots 0-2
        return;
    }
    const int b = bid >> 5;
    const int pxg = (bid >> 1) & 15;
    const int coh = bid & 1;
    const int y0 = pxg * 2;
    const float* in = p.mem + (size_t)b * 131072;
    const f16* wfo = p.wfo + (size_t)l * 409600;

    const int ci_l = tid & 31, sr = tid >> 5;
    const int skg = ci_l >> 3, scb = ci_l & 7;
    const int sy = y0 - 2 + sr;
    const bool rowok = (sr < 6) && ((unsigned)sy < 32u);

    const int w = tid >> 6, lane = tid & 63;
    const int coq = w & 1, wr = w >> 1;
    const int n = lane & 15, kq = lane >> 4;
    const size_t wtap = (size_t)2 * 64 * 128;
    const int pbase = (wr + 2) * 37 + 2 + n;

    f32x4 acc[2] = {};

    for (int chunk = 0; chunk < 4; ++chunk) {
        __syncthreads();
        {
            const int cig = chunk * 32 + ci_l;
            float v[32];
            #pragma unroll
            for (int k = 0; k < 32; ++k) v[k] = 0.f;
            if (rowok) {
                const float* rp = in + (size_t)cig * 1024 + sy * 32;
                #pragma unroll
                for (int k = 0; k < 8; ++k) {
                    float4 q = *(const float4*)(rp + k * 4);
                    v[4 * k + 0] = q.x; v[4 * k + 1] = q.y;
                    v[4 * k + 2] = q.z; v[4 * k + 3] = q.w;
                }
            }
            if (sr < 6) {
                #define STW(c, val) { int pp = sr * 37 + (c);                        \
                    int s_ = skg ^ ((pp >> 1) & 3);                                  \
                    int off = pp * 32 + (s_ << 3) + scb;                             \
                    f16 hi = (f16)(val); f16 lo = (f16)((val) - (float)hi);          \
                    lds[off] = hi; lds[7104 + off] = lo; }
                STW(0, 0.f); STW(1, 0.f);
                #pragma unroll
                for (int x = 0; x < 32; ++x) STW(x + 2, v[x]);
                STW(34, 0.f); STW(35, 0.f);
                #undef STW
            }
        }
        __syncthreads();
        const size_t laneA = (size_t)(coh * 32 + coq * 16 + n) * 128 + chunk * 32 + kq * 8;
        for (int ky = 0; ky < 5; ++ky) {
            const f16* wfk = wfo + (size_t)(ky * 5) * wtap;
            const int pky = pbase + (ky - 2) * 37;
            #pragma unroll
            for (int kx = 0; kx < 5; ++kx) {
                const f16* wA = wfk + (size_t)kx * wtap;
                f16x8 ah = *(const f16x8*)(wA + laneA);
                f16x8 al = *(const f16x8*)(wA + (size_t)64 * 128 + laneA);
                #pragma unroll
                for (int pt = 0; pt < 2; ++pt) {
                    int pp = pky + (kx - 2) + pt * 16;
                    int off = pp * 32 + ((kq ^ ((pp >> 1) & 3)) << 3);
                    f16x8 bh = *(const f16x8*)&lds[off];
                    f16x8 bl = *(const f16x8*)&lds[7104 + off];
                    acc[pt] = __builtin_amdgcn_mfma_f32_16x16x32_f16(ah, bh, acc[pt], 0, 0, 0);
                    acc[pt] = __builtin_amdgcn_mfma_f32_16x16x32_f16(al, bh, acc[pt], 0, 0, 0);
                    acc[pt] = __builtin_amdgcn_mfma_f32_16x16x32_f16(ah, bl, acc[pt], 0, 0, 0);
                }
            }
        }
    }

    float* ob = p.oraw + ((size_t)b * 64 + coh * 32 + coq * 16) * 1024 + (y0 + wr) * 32;
    double s1 = 0.0, s2 = 0.0;
    #pragma unroll
    for (int pt = 0; pt < 2; ++pt)
        #pragma unroll
        for (int j = 0; j < 4; ++j) {
            float vv = acc[pt][j];
            ob[(size_t)(kq * 4 + j) * 1024 + pt * 16 + n] = vv;
            s1 += vv; s2 += (double)vv * vv;
        }
    __syncthreads();
    double* red = (double*)lds;
    red[tid] = s1; red[256 + tid] = s2;
    __syncthreads();
    for (int s = 128; s > 0; s >>= 1) {
        if (tid < s) { red[tid] += red[tid + s]; red[256 + tid] += red[256 + tid + s]; }
        __syncthreads();
    }
    if (tid == 0) {
        atomicAdd(&p.stats[24 + b * 2 + 0], red[0]);
        atomicAdd(&p.stats[24 + b * 2 + 1], red[256]);
    }
}

// ---------- phase D: o-gate + 1x1 conv_last + h_new (256 units) ------------
__device__ __forceinline__ void phaseD(const P& p, int l) {
    const int bid = blockIdx.x;
    if (bid >= 256) return;
    const int tid = threadIdx.x;
    const int b = bid >> 6;
    const int pxq = (bid >> 2) & 15;
    const int coq = bid & 3;
    const int px = pxq * 64 + (tid & 63);
    const int co0 = coq * 16 + (tid >> 6) * 4;
    const float* memb = p.mem + (size_t)b * 131072 + px;
    const float* Wl_l = p.Wl + (size_t)l * 8192;
    float acc[4] = {0.f, 0.f, 0.f, 0.f};
    for (int ci = 0; ci < 128; ++ci) {
        float v = memb[ci * 1024];
        #pragma unroll
        for (int k = 0; k < 4; ++k)
            acc[k] = fmaf(v, Wl_l[(co0 + k) * 128 + ci], acc[k]);
    }
    float mu, rs;
    ln_params(p.stats, 3, b, 65536.f, mu, rs);
    float* hs_l = p.hs + (size_t)l * 262144;
    #pragma unroll
    for (int k = 0; k < 4; ++k) {
        size_t idx = ((size_t)b * 64 + co0 + k) * 1024 + px;
        float o = sigmoidf_(p.oxh[idx] + (p.oraw[idx] - mu) * rs);
        hs_l[idx] = o * fast_tanh(acc[k]);
    }
}

// ----------------- phase OUT: 1x1 output conv (64 -> 16) -------------------
__device__ __forceinline__ void phaseOUT(const P& p, int t) {
    int gid = blockIdx.x * 256 + threadIdx.x;
    if (gid >= 4096) return;
    int b = gid >> 10, px = gid & 1023;
    const float* hb = p.hs + (size_t)3 * 262144 + (size_t)b * 65536 + px;
    float acc[16];
    #pragma unroll
    for (int k = 0; k < 16; ++k) acc[k] = 0.f;
    for (int ci = 0; ci < 64; ++ci) {
        float v = hb[ci * 1024];
        #pragma unroll
        for (int k = 0; k < 16; ++k) acc[k] = fmaf(v, p.Wout[k * 64 + ci], acc[k]);
    }
    #pragma unroll
    for (int k = 0; k < 16; ++k)
        p.out[(((size_t)b * NSTEP + t) * 16 + k) * 1024 + px] = acc[k];
}

// ------------------------------ megakernel ---------------------------------
__global__ __launch_bounds__(256, 2)
void mega_k(P p) {
    __shared__ alignas(16) f16 lds[14208];

    // ---- prologue: zero state/stats + weight prep ----
    {
        const int gid = blockIdx.x * 256 + threadIdx.x;
        const int gs = GRID * 256;
        float4 z = make_float4(0.f, 0.f, 0.f, 0.f);
        for (size_t i = (size_t)gid * 4; i < ZERO_N; i += (size_t)gs * 4)
            *reinterpret_cast<float4*>(p.hs + i) = z;
        prep_dev(p.Wx0, p.wfx0, 448, 16, 32, gid, gs);
        for (int lr = 0; lr < 3; ++lr)
            prep_dev(p.Wxr + (size_t)lr * 716800, p.wfxr + (size_t)lr * 1433600,
                     448, 64, 64, gid, gs);
        for (int l = 0; l < 4; ++l) {
            prep_dev(p.Wh + (size_t)l * 409600, p.wfh + (size_t)l * 819200,
                     256, 64, 64, gid, gs);
            prep_dev(p.Wm + (size_t)l * 307200, p.wfm + (size_t)l * 614400,
                     192, 64, 64, gid, gs);
            prep_dev(p.Wo + (size_t)l * 204800, p.wfo + (size_t)l * 409600,
                     64, 128, 128, gid, gs);
        }
    }
    unsigned gen = 0;
    gridbar(p.bar, ++gen);

    for (int t = 0; t < NSTEP; ++t) {
        for (int l = 0; l < NLAYER; ++l) {
            for (int u = blockIdx.x; u < 896; u += GRID)
                phaseA(p, lds, t, l, u);
            gridbar(p.bar, ++gen);
            phaseB(p, l);
            gridbar(p.bar, ++gen);
            phaseC(p, lds, l);
            gridbar(p.bar, ++gen);
            phaseD(p, l);
            gridbar(p.bar, ++gen);
        }
        phaseOUT(p, t);
        gridbar(p.bar, ++gen);
    }
}

// ---------------------------------------------------------------------------
extern "C" void kernel_launch(void* const* d_in, const int* in_sizes, int n_in,
                              void* d_out, int out_size, void* d_ws, size_t ws_size,
                              hipStream_t stream) {
    float* ws = (float*)d_ws;
    P pv;
    pv.x_patched = (const float*)d_in[0];
    pv.mask      = (const float*)d_in[1];
    pv.Wx0       = (const float*)d_in[2];
    pv.Wxr       = (const float*)d_in[3];
    pv.Wh        = (const float*)d_in[4];
    pv.Wm        = (const float*)d_in[5];
    pv.Wo        = (const float*)d_in[6];
    pv.Wl        = (const float*)d_in[7];
    pv.Wout      = (const float*)d_in[8];
    pv.out   = (float*)d_out;
    pv.hs    = ws + OFF_HS;
    pv.cs    = ws + OFF_CS;
    pv.m_buf = ws + OFF_M;
    pv.stats = (double*)(ws + OFF_STATS);
    pv.xraw  = ws + OFF_XRAW;
    pv.hraw  = ws + OFF_HRAW;
    pv.mraw  = ws + OFF_MRAW;
    pv.mem   = ws + OFF_MEM;
    pv.oraw  = ws + OFF_ORAW;
    pv.oxh   = ws + OFF_OXH;
    f16* wfb = (f16*)(ws + OFF_WF);
    pv.wfx0 = wfb + WF_X0;
    pv.wfxr = wfb + WF_XR;
    pv.wfh  = wfb + WF_H;
    pv.wfm  = wfb + WF_M;
    pv.wfo  = wfb + WF_O;
    pv.bar  = (unsigned*)(ws + OFF_BAR);

    // barrier state must start at 0 (d_ws is poisoned before every launch)
    hipMemsetAsync((void*)pv.bar, 0, BAR_BYTES, stream);

    mega_k<<<dim3(GRID), dim3(256), 0, stream>>>(pv);

    (void)in_sizes; (void)n_in; (void)out_size; (void)ws_size;
}